// Round 8
// baseline (486.663 us; speedup 1.0000x reference)
//
#include <hip/hip_runtime.h>
#include <hip/hip_cooperative_groups.h>
#include <math.h>

namespace cg = cooperative_groups;

#define KNN 16
#define CH 64
#define HID 16
#define NEG_BIG (-3.402823466e+38f)

__device__ __forceinline__ float sigmoidf_(float x) {
    return 1.0f / (1.0f + __expf(-x));
}

// pack two fp32 into bf16x2 (RNE), a in low16, b in high16
__device__ __forceinline__ unsigned int pack_bf2(float a, float b) {
    unsigned int ua = __float_as_uint(a), ub = __float_as_uint(b);
    ua = (ua + 0x7FFFu + ((ua >> 16) & 1u)) >> 16;
    ub = (ub + 0x7FFFu + ((ub >> 16) & 1u)) & 0xFFFF0000u;
    return ua | ub;
}

// unpack 4 packed bf16 -> float4
__device__ __forceinline__ float4 bf4_to_f4(unsigned int lo, unsigned int hi) {
    float4 r;
    r.x = __uint_as_float(lo << 16);
    r.y = __uint_as_float(lo & 0xFFFF0000u);
    r.z = __uint_as_float(hi << 16);
    r.w = __uint_as_float(hi & 0xFFFF0000u);
    return r;
}

// paired fold-reduce across an 8-lane group: A[8],B[8] partials -> lane sub
// ends holding full sums A -> H[sub], B -> H[sub+8].
__device__ __forceinline__ void fold8_2(float A[8], float B[8], int sub) {
    #pragma unroll
    for (int m = 4; m >= 1; m >>= 1) {
        bool hi = (sub & m) != 0;
        #pragma unroll
        for (int i = 0; i < m; ++i) {
            float sA = hi ? A[i] : A[i + m], kA_ = hi ? A[i + m] : A[i];
            A[i] = kA_ + __shfl_xor(sA, m);
            float sB = hi ? B[i] : B[i + m], kB_ = hi ? B[i + m] : B[i];
            B[i] = kB_ + __shfl_xor(sB, m);
        }
    }
}

// Single cooperative kernel: X (bf16 table) -> A (channel attn) -> B (knn
// stats) -> C (sparse conv + scale), separated by grid.sync(). R7 showed the
// 4-launch pipeline pays ~65-75us of inter-dispatch dead time (tail constant
// ~110us across all configs while phase-sum is ~95us); fusing removes 3 hops.
// Phase bodies are R7's proven kernels, only re-skinned as grid-stride loops.
__global__ __launch_bounds__(256, 4) void kFused(
        const float4* __restrict__ xv, uint2* __restrict__ xb,
        const float* __restrict__ W1, const float* __restrict__ b1,
        const float* __restrict__ W2, const float* __restrict__ b2,
        const int* __restrict__ idx, const int* __restrict__ cidx,
        const float* __restrict__ conv_w,
        float4* __restrict__ outse, float2* __restrict__ rowstat,
        float2* __restrict__ zz, float4* __restrict__ out, int n) {
    cg::grid_group grid = cg::this_grid();

    __shared__ float4 w1a[128];   // w1a[h*8+s] = W1[(8s+0..3)][h]
    __shared__ float4 w1b[128];   // w1b[h*8+s] = W1[(8s+4..7)][h]
    __shared__ float4 w2q[256];   // float4 copy of W2 (16x64 row-major)
    __shared__ float cw[54];
    __shared__ float sgate[256];

    int t = threadIdx.x;
    const int gsz = gridDim.x * 256;
    const int gid = blockIdx.x * 256 + t;

    // ---- weights to LDS (once) ----
    if (t < 128) {
        int h = t >> 3, s = t & 7;
        float4 a, b;
        a.x = W1[(8 * s + 0) * HID + h];
        a.y = W1[(8 * s + 1) * HID + h];
        a.z = W1[(8 * s + 2) * HID + h];
        a.w = W1[(8 * s + 3) * HID + h];
        b.x = W1[(8 * s + 4) * HID + h];
        b.y = W1[(8 * s + 5) * HID + h];
        b.z = W1[(8 * s + 6) * HID + h];
        b.w = W1[(8 * s + 7) * HID + h];
        w1a[t] = a;
        w1b[t] = b;
    }
    if (t < 54) cw[t] = conv_w[t];
    w2q[t] = ((const float4*)W2)[t];
    __syncthreads();

    // ---- phase X: bf16 copy of x_F ----
    int n16 = n * 16;
    for (int i = gid; i < n16; i += gsz) {
        float4 v = xv[i];
        uint2 r;
        r.x = pack_bf2(v.x, v.y);
        r.y = pack_bf2(v.z, v.w);
        xb[i] = r;
    }
    grid.sync();

    // ---- phase A: channel attention (R7 body; 8 lanes/point) ----
    {
        const uint4* xb4 = (const uint4*)xb;
        const int2* idx2 = (const int2*)idx;
        int sub = t & 7;
        int nPG = (n + 31) / 32;
        for (int pg = blockIdx.x; pg < nPG; pg += gridDim.x) {
            int p = pg * 32 + (t >> 3);
            if (p < n) {
                int2 jp = idx2[(size_t)p * 8 + sub];
                int jA[8], jB[8];
                #pragma unroll
                for (int s = 0; s < 8; ++s) {
                    jA[s] = __shfl(jp.x, s, 8);
                    jB[s] = __shfl(jp.y, s, 8);
                }
                uint4 va[8], vb[8];
                #pragma unroll
                for (int s = 0; s < 8; ++s) va[s] = xb4[(size_t)jA[s] * 8 + sub];
                #pragma unroll
                for (int s = 0; s < 8; ++s) vb[s] = xb4[(size_t)jB[s] * 8 + sub];
                float4 own0 = xv[(size_t)p * 16 + 2 * sub];
                float4 own1 = xv[(size_t)p * 16 + 2 * sub + 1];
                float b1a = b1[sub], b1b = b1[sub + 8];
                float4 bq0 = ((const float4*)b2)[2 * sub];
                float4 bq1 = ((const float4*)b2)[2 * sub + 1];
                __builtin_amdgcn_sched_barrier(0);

                float4 sumLo, sumHi, mxLo, mxHi;
                {
                    float4 lo = bf4_to_f4(va[0].x, va[0].y);
                    float4 hi = bf4_to_f4(va[0].z, va[0].w);
                    sumLo = lo; mxLo = lo; sumHi = hi; mxHi = hi;
                }
                #pragma unroll
                for (int s = 1; s < 8; ++s) {
                    float4 lo = bf4_to_f4(va[s].x, va[s].y);
                    float4 hi = bf4_to_f4(va[s].z, va[s].w);
                    sumLo.x += lo.x; sumLo.y += lo.y; sumLo.z += lo.z; sumLo.w += lo.w;
                    sumHi.x += hi.x; sumHi.y += hi.y; sumHi.z += hi.z; sumHi.w += hi.w;
                    mxLo.x = fmaxf(mxLo.x, lo.x); mxLo.y = fmaxf(mxLo.y, lo.y);
                    mxLo.z = fmaxf(mxLo.z, lo.z); mxLo.w = fmaxf(mxLo.w, lo.w);
                    mxHi.x = fmaxf(mxHi.x, hi.x); mxHi.y = fmaxf(mxHi.y, hi.y);
                    mxHi.z = fmaxf(mxHi.z, hi.z); mxHi.w = fmaxf(mxHi.w, hi.w);
                }
                #pragma unroll
                for (int s = 0; s < 8; ++s) {
                    float4 lo = bf4_to_f4(vb[s].x, vb[s].y);
                    float4 hi = bf4_to_f4(vb[s].z, vb[s].w);
                    sumLo.x += lo.x; sumLo.y += lo.y; sumLo.z += lo.z; sumLo.w += lo.w;
                    sumHi.x += hi.x; sumHi.y += hi.y; sumHi.z += hi.z; sumHi.w += hi.w;
                    mxLo.x = fmaxf(mxLo.x, lo.x); mxLo.y = fmaxf(mxLo.y, lo.y);
                    mxLo.z = fmaxf(mxLo.z, lo.z); mxLo.w = fmaxf(mxLo.w, lo.w);
                    mxHi.x = fmaxf(mxHi.x, hi.x); mxHi.y = fmaxf(mxHi.y, hi.y);
                    mxHi.z = fmaxf(mxHi.z, hi.z); mxHi.w = fmaxf(mxHi.w, hi.w);
                }
                const float inv_k = 1.0f / KNN;
                float4 meLo = {sumLo.x * inv_k, sumLo.y * inv_k, sumLo.z * inv_k, sumLo.w * inv_k};
                float4 meHi = {sumHi.x * inv_k, sumHi.y * inv_k, sumHi.z * inv_k, sumHi.w * inv_k};

                float Hm_a, Hm_b, Hx_a, Hx_b;
                {
                    float A[8], B[8];
                    #pragma unroll
                    for (int h = 0; h < 8; ++h) {
                        float4 wa = w1a[h * 8 + sub], wb = w1b[h * 8 + sub];
                        A[h] = meLo.x * wa.x + meLo.y * wa.y + meLo.z * wa.z + meLo.w * wa.w
                             + meHi.x * wb.x + meHi.y * wb.y + meHi.z * wb.z + meHi.w * wb.w;
                        float4 wa2 = w1a[(h + 8) * 8 + sub], wb2 = w1b[(h + 8) * 8 + sub];
                        B[h] = meLo.x * wa2.x + meLo.y * wa2.y + meLo.z * wa2.z + meLo.w * wa2.w
                             + meHi.x * wb2.x + meHi.y * wb2.y + meHi.z * wb2.z + meHi.w * wb2.w;
                    }
                    fold8_2(A, B, sub);
                    Hm_a = A[0]; Hm_b = B[0];
                }
                {
                    float A[8], B[8];
                    #pragma unroll
                    for (int h = 0; h < 8; ++h) {
                        float4 wa = w1a[h * 8 + sub], wb = w1b[h * 8 + sub];
                        A[h] = mxLo.x * wa.x + mxLo.y * wa.y + mxLo.z * wa.z + mxLo.w * wa.w
                             + mxHi.x * wb.x + mxHi.y * wb.y + mxHi.z * wb.z + mxHi.w * wb.w;
                        float4 wa2 = w1a[(h + 8) * 8 + sub], wb2 = w1b[(h + 8) * 8 + sub];
                        B[h] = mxLo.x * wa2.x + mxLo.y * wa2.y + mxLo.z * wa2.z + mxLo.w * wa2.w
                             + mxHi.x * wb2.x + mxHi.y * wb2.y + mxHi.z * wb2.z + mxHi.w * wb2.w;
                    }
                    fold8_2(A, B, sub);
                    Hx_a = A[0]; Hx_b = B[0];
                }
                float H_a = fmaxf(Hm_a + b1a, 0.0f) + fmaxf(Hx_a + b1a, 0.0f);
                float H_b = fmaxf(Hm_b + b1b, 0.0f) + fmaxf(Hx_b + b1b, 0.0f);

                float4 a0 = {0.f, 0.f, 0.f, 0.f}, a1 = {0.f, 0.f, 0.f, 0.f};
                #pragma unroll
                for (int h = 0; h < 8; ++h) {
                    float Hh = __shfl(H_a, h, 8);
                    float4 w0 = w2q[h * 16 + 2 * sub], w1v = w2q[h * 16 + 2 * sub + 1];
                    a0.x += Hh * w0.x; a0.y += Hh * w0.y; a0.z += Hh * w0.z; a0.w += Hh * w0.w;
                    a1.x += Hh * w1v.x; a1.y += Hh * w1v.y; a1.z += Hh * w1v.z; a1.w += Hh * w1v.w;
                }
                #pragma unroll
                for (int h = 0; h < 8; ++h) {
                    float Hh = __shfl(H_b, h, 8);
                    float4 w0 = w2q[(h + 8) * 16 + 2 * sub], w1v = w2q[(h + 8) * 16 + 2 * sub + 1];
                    a0.x += Hh * w0.x; a0.y += Hh * w0.y; a0.z += Hh * w0.z; a0.w += Hh * w0.w;
                    a1.x += Hh * w1v.x; a1.y += Hh * w1v.y; a1.z += Hh * w1v.z; a1.w += Hh * w1v.w;
                }
                float4 o0, o1;
                o0.x = own0.x * sigmoidf_(a0.x + 2.0f * bq0.x);
                o0.y = own0.y * sigmoidf_(a0.y + 2.0f * bq0.y);
                o0.z = own0.z * sigmoidf_(a0.z + 2.0f * bq0.z);
                o0.w = own0.w * sigmoidf_(a0.w + 2.0f * bq0.w);
                o1.x = own1.x * sigmoidf_(a1.x + 2.0f * bq1.x);
                o1.y = own1.y * sigmoidf_(a1.y + 2.0f * bq1.y);
                o1.z = own1.z * sigmoidf_(a1.z + 2.0f * bq1.z);
                o1.w = own1.w * sigmoidf_(a1.w + 2.0f * bq1.w);
                outse[(size_t)p * 16 + 2 * sub] = o0;
                outse[(size_t)p * 16 + 2 * sub + 1] = o1;

                float sm = (o0.x + o0.y + o0.z + o0.w) + (o1.x + o1.y + o1.z + o1.w);
                float sx = fmaxf(fmaxf(fmaxf(o0.x, o0.y), fmaxf(o0.z, o0.w)),
                                 fmaxf(fmaxf(o1.x, o1.y), fmaxf(o1.z, o1.w)));
                #pragma unroll
                for (int m = 4; m >= 1; m >>= 1) {
                    sm += __shfl_xor(sm, m);
                    sx = fmaxf(sx, __shfl_xor(sx, m));
                }
                if (sub == 0) rowstat[p] = make_float2(sm * (1.0f / 64.0f), sx);
            }
        }
    }
    grid.sync();

    // ---- phase B: knn stats pooling (2 lanes/point) ----
    {
        const int4* idxv = (const int4*)idx;
        int two_n = 2 * n;
        for (int tt = gid; tt < two_n; tt += gsz) {
            int i = tt >> 1, half = tt & 1;
            int4 a = idxv[(size_t)i * 4 + half * 2];
            int4 b = idxv[(size_t)i * 4 + half * 2 + 1];
            float2 s0 = rowstat[a.x], s1 = rowstat[a.y], s2 = rowstat[a.z], s3 = rowstat[a.w];
            float2 s4 = rowstat[b.x], s5 = rowstat[b.y], s6 = rowstat[b.z], s7 = rowstat[b.w];
            float zm = (s0.x + s1.x) + (s2.x + s3.x) + ((s4.x + s5.x) + (s6.x + s7.x));
            float zx = fmaxf(fmaxf(fmaxf(s0.y, s1.y), fmaxf(s2.y, s3.y)),
                             fmaxf(fmaxf(s4.y, s5.y), fmaxf(s6.y, s7.y)));
            zm += __shfl_xor(zm, 1);
            zx = fmaxf(zx, __shfl_xor(zx, 1));
            if (half == 0) zz[i] = make_float2(zm * (1.0f / 16.0f), zx);
        }
    }
    grid.sync();

    // ---- phase C: 27-tap sparse conv -> sigmoid gate -> scale outse ----
    {
        int nCh = (n + 255) / 256;
        for (int c = blockIdx.x; c < nCh; c += gridDim.x) {
            int base = c * 256;
            int i = base + t;
            if (i < n) {
                float acc = 0.0f;
                #pragma unroll
                for (int k = 0; k < 27; ++k) {
                    int j = cidx[(size_t)i * 27 + k];   // branchless clamp + mask
                    int jc = j >= 0 ? j : 0;
                    float msk = j >= 0 ? 1.0f : 0.0f;
                    float2 zv = zz[jc];
                    acc += msk * (zv.x * cw[2 * k] + zv.y * cw[2 * k + 1]);
                }
                sgate[t] = sigmoidf_(acc);
            }
            __syncthreads();
            int npts = n - base; if (npts > 256) npts = 256;
            int tot = npts * 16;                        // float4s this chunk owns
            for (int q = t; q < tot; q += 256) {
                float s = sgate[q >> 4];
                float4 v = outse[(size_t)base * 16 + q];
                out[(size_t)base * 16 + q] = make_float4(v.x * s, v.y * s, v.z * s, v.w * s);
            }
            __syncthreads();   // protect sgate before next chunk reuses it
        }
    }
}

extern "C" void kernel_launch(void* const* d_in, const int* in_sizes, int n_in,
                              void* d_out, int out_size, void* d_ws, size_t ws_size,
                              hipStream_t stream) {
    const float* x_F    = (const float*)d_in[0];
    const float* W1     = (const float*)d_in[1];
    const float* b1     = (const float*)d_in[2];
    const float* W2     = (const float*)d_in[3];
    const float* b2     = (const float*)d_in[4];
    const float* conv_w = (const float*)d_in[5];
    const int*   idx    = (const int*)d_in[6];
    const int*   cidx   = (const int*)d_in[7];
    int n = in_sizes[0] / CH;   // 100000

    char* ws = (char*)d_ws;
    size_t off = 0;
    uint2*  xb      = (uint2*)(ws + off);  off += (size_t)n * CH * 2;   // bf16 table
    float*  outse   = (float*)(ws + off);  off += (size_t)n * CH * 4;
    float2* rowstat = (float2*)(ws + off); off += (size_t)n * 8;
    float2* zz      = (float2*)(ws + off); off += (size_t)n * 8;

    const float4* xv = (const float4*)x_F;
    float4* outsev = (float4*)outse;
    float4* outv = (float4*)d_out;

    // co-resident grid: occupancy query (pure host-side, deterministic)
    int perCU = 0;
    hipError_t e = hipOccupancyMaxActiveBlocksPerMultiprocessor(
        &perCU, reinterpret_cast<const void*>(kFused), 256, 0);
    if (e != hipSuccess || perCU < 1) perCU = 2;
    if (perCU > 8) perCU = 8;
    int grid = perCU * 256;   // 256 CUs on MI355X

    void* args[] = {(void*)&xv, (void*)&xb, (void*)&W1, (void*)&b1, (void*)&W2,
                    (void*)&b2, (void*)&idx, (void*)&cidx, (void*)&conv_w,
                    (void*)&outsev, (void*)&rowstat, (void*)&zz, (void*)&outv,
                    (void*)&n};
    hipLaunchCooperativeKernel(reinterpret_cast<void*>(kFused),
                               dim3(grid), dim3(256), args, 0, stream);
}

// Round 9
// 317.458 us; speedup vs baseline: 1.5330x; 1.5330x over previous
//
#include <hip/hip_runtime.h>
#include <hip/hip_cooperative_groups.h>
#include <math.h>

namespace cg = cooperative_groups;

#define KNN 16
#define CH 64
#define HID 16
#define NEG_BIG (-3.402823466e+38f)

__device__ __forceinline__ float sigmoidf_(float x) {
    return 1.0f / (1.0f + __expf(-x));
}

// pack two fp32 into bf16x2 (RNE), a in low16, b in high16
__device__ __forceinline__ unsigned int pack_bf2(float a, float b) {
    unsigned int ua = __float_as_uint(a), ub = __float_as_uint(b);
    ua = (ua + 0x7FFFu + ((ua >> 16) & 1u)) >> 16;
    ub = (ub + 0x7FFFu + ((ub >> 16) & 1u)) & 0xFFFF0000u;
    return ua | ub;
}

// unpack 4 packed bf16 -> float4
__device__ __forceinline__ float4 bf4_to_f4(unsigned int lo, unsigned int hi) {
    float4 r;
    r.x = __uint_as_float(lo << 16);
    r.y = __uint_as_float(lo & 0xFFFF0000u);
    r.z = __uint_as_float(hi << 16);
    r.w = __uint_as_float(hi & 0xFFFF0000u);
    return r;
}

// paired fold-reduce across an 8-lane group: A[8],B[8] partials -> lane sub
// ends holding full sums A -> H[sub], B -> H[sub+8].
__device__ __forceinline__ void fold8_2(float A[8], float B[8], int sub) {
    #pragma unroll
    for (int m = 4; m >= 1; m >>= 1) {
        bool hi = (sub & m) != 0;
        #pragma unroll
        for (int i = 0; i < m; ++i) {
            float sA = hi ? A[i] : A[i + m], kA_ = hi ? A[i + m] : A[i];
            A[i] = kA_ + __shfl_xor(sA, m);
            float sB = hi ? B[i] : B[i + m], kB_ = hi ? B[i + m] : B[i];
            B[i] = kB_ + __shfl_xor(sB, m);
        }
    }
}

// Single cooperative kernel: X (bf16 table) -> A (channel attn) -> B (knn
// stats) -> C (sparse conv + scale), separated by grid.sync().
// launch_bounds(256,3): R8's (256,4) capped the allocator at 64 VGPRs, below
// phase A's 64-reg gather payload -> ~120MB/side scratch spills and a 3x
// regression. (256,3) is the bound under which this exact phase-A body
// compiled spill-free at 84 VGPRs in R7.
__global__ __launch_bounds__(256, 3) void kFused(
        const float4* __restrict__ xv, uint2* __restrict__ xb,
        const float* __restrict__ W1, const float* __restrict__ b1,
        const float* __restrict__ W2, const float* __restrict__ b2,
        const int* __restrict__ idx, const int* __restrict__ cidx,
        const float* __restrict__ conv_w,
        float4* __restrict__ outse, float2* __restrict__ rowstat,
        float2* __restrict__ zz, float4* __restrict__ out, int n) {
    cg::grid_group grid = cg::this_grid();

    __shared__ float4 w1a[128];   // w1a[h*8+s] = W1[(8s+0..3)][h]
    __shared__ float4 w1b[128];   // w1b[h*8+s] = W1[(8s+4..7)][h]
    __shared__ float4 w2q[256];   // float4 copy of W2 (16x64 row-major)
    __shared__ float cw[54];
    __shared__ float sgate[256];

    int t = threadIdx.x;
    const int gsz = gridDim.x * 256;
    const int gid = blockIdx.x * 256 + t;

    // ---- weights to LDS (once) ----
    if (t < 128) {
        int h = t >> 3, s = t & 7;
        float4 a, b;
        a.x = W1[(8 * s + 0) * HID + h];
        a.y = W1[(8 * s + 1) * HID + h];
        a.z = W1[(8 * s + 2) * HID + h];
        a.w = W1[(8 * s + 3) * HID + h];
        b.x = W1[(8 * s + 4) * HID + h];
        b.y = W1[(8 * s + 5) * HID + h];
        b.z = W1[(8 * s + 6) * HID + h];
        b.w = W1[(8 * s + 7) * HID + h];
        w1a[t] = a;
        w1b[t] = b;
    }
    if (t < 54) cw[t] = conv_w[t];
    w2q[t] = ((const float4*)W2)[t];
    __syncthreads();

    // ---- phase X: bf16 copy of x_F ----
    int n16 = n * 16;
    for (int i = gid; i < n16; i += gsz) {
        float4 v = xv[i];
        uint2 r;
        r.x = pack_bf2(v.x, v.y);
        r.y = pack_bf2(v.z, v.w);
        xb[i] = r;
    }
    grid.sync();

    // ---- phase A: channel attention (R7 body; 8 lanes/point) ----
    {
        const uint4* xb4 = (const uint4*)xb;
        const int2* idx2 = (const int2*)idx;
        int sub = t & 7;
        int nPG = (n + 31) / 32;
        for (int pg = blockIdx.x; pg < nPG; pg += gridDim.x) {
            int p = pg * 32 + (t >> 3);
            if (p < n) {
                int2 jp = idx2[(size_t)p * 8 + sub];
                int jA[8], jB[8];
                #pragma unroll
                for (int s = 0; s < 8; ++s) {
                    jA[s] = __shfl(jp.x, s, 8);
                    jB[s] = __shfl(jp.y, s, 8);
                }
                uint4 va[8], vb[8];
                #pragma unroll
                for (int s = 0; s < 8; ++s) va[s] = xb4[(size_t)jA[s] * 8 + sub];
                #pragma unroll
                for (int s = 0; s < 8; ++s) vb[s] = xb4[(size_t)jB[s] * 8 + sub];
                float4 own0 = xv[(size_t)p * 16 + 2 * sub];
                float4 own1 = xv[(size_t)p * 16 + 2 * sub + 1];
                float b1a = b1[sub], b1b = b1[sub + 8];
                float4 bq0 = ((const float4*)b2)[2 * sub];
                float4 bq1 = ((const float4*)b2)[2 * sub + 1];
                __builtin_amdgcn_sched_barrier(0);

                float4 sumLo, sumHi, mxLo, mxHi;
                {
                    float4 lo = bf4_to_f4(va[0].x, va[0].y);
                    float4 hi = bf4_to_f4(va[0].z, va[0].w);
                    sumLo = lo; mxLo = lo; sumHi = hi; mxHi = hi;
                }
                #pragma unroll
                for (int s = 1; s < 8; ++s) {
                    float4 lo = bf4_to_f4(va[s].x, va[s].y);
                    float4 hi = bf4_to_f4(va[s].z, va[s].w);
                    sumLo.x += lo.x; sumLo.y += lo.y; sumLo.z += lo.z; sumLo.w += lo.w;
                    sumHi.x += hi.x; sumHi.y += hi.y; sumHi.z += hi.z; sumHi.w += hi.w;
                    mxLo.x = fmaxf(mxLo.x, lo.x); mxLo.y = fmaxf(mxLo.y, lo.y);
                    mxLo.z = fmaxf(mxLo.z, lo.z); mxLo.w = fmaxf(mxLo.w, lo.w);
                    mxHi.x = fmaxf(mxHi.x, hi.x); mxHi.y = fmaxf(mxHi.y, hi.y);
                    mxHi.z = fmaxf(mxHi.z, hi.z); mxHi.w = fmaxf(mxHi.w, hi.w);
                }
                #pragma unroll
                for (int s = 0; s < 8; ++s) {
                    float4 lo = bf4_to_f4(vb[s].x, vb[s].y);
                    float4 hi = bf4_to_f4(vb[s].z, vb[s].w);
                    sumLo.x += lo.x; sumLo.y += lo.y; sumLo.z += lo.z; sumLo.w += lo.w;
                    sumHi.x += hi.x; sumHi.y += hi.y; sumHi.z += hi.z; sumHi.w += hi.w;
                    mxLo.x = fmaxf(mxLo.x, lo.x); mxLo.y = fmaxf(mxLo.y, lo.y);
                    mxLo.z = fmaxf(mxLo.z, lo.z); mxLo.w = fmaxf(mxLo.w, lo.w);
                    mxHi.x = fmaxf(mxHi.x, hi.x); mxHi.y = fmaxf(mxHi.y, hi.y);
                    mxHi.z = fmaxf(mxHi.z, hi.z); mxHi.w = fmaxf(mxHi.w, hi.w);
                }
                const float inv_k = 1.0f / KNN;
                float4 meLo = {sumLo.x * inv_k, sumLo.y * inv_k, sumLo.z * inv_k, sumLo.w * inv_k};
                float4 meHi = {sumHi.x * inv_k, sumHi.y * inv_k, sumHi.z * inv_k, sumHi.w * inv_k};

                float Hm_a, Hm_b, Hx_a, Hx_b;
                {
                    float A[8], B[8];
                    #pragma unroll
                    for (int h = 0; h < 8; ++h) {
                        float4 wa = w1a[h * 8 + sub], wb = w1b[h * 8 + sub];
                        A[h] = meLo.x * wa.x + meLo.y * wa.y + meLo.z * wa.z + meLo.w * wa.w
                             + meHi.x * wb.x + meHi.y * wb.y + meHi.z * wb.z + meHi.w * wb.w;
                        float4 wa2 = w1a[(h + 8) * 8 + sub], wb2 = w1b[(h + 8) * 8 + sub];
                        B[h] = meLo.x * wa2.x + meLo.y * wa2.y + meLo.z * wa2.z + meLo.w * wa2.w
                             + meHi.x * wb2.x + meHi.y * wb2.y + meHi.z * wb2.z + meHi.w * wb2.w;
                    }
                    fold8_2(A, B, sub);
                    Hm_a = A[0]; Hm_b = B[0];
                }
                {
                    float A[8], B[8];
                    #pragma unroll
                    for (int h = 0; h < 8; ++h) {
                        float4 wa = w1a[h * 8 + sub], wb = w1b[h * 8 + sub];
                        A[h] = mxLo.x * wa.x + mxLo.y * wa.y + mxLo.z * wa.z + mxLo.w * wa.w
                             + mxHi.x * wb.x + mxHi.y * wb.y + mxHi.z * wb.z + mxHi.w * wb.w;
                        float4 wa2 = w1a[(h + 8) * 8 + sub], wb2 = w1b[(h + 8) * 8 + sub];
                        B[h] = mxLo.x * wa2.x + mxLo.y * wa2.y + mxLo.z * wa2.z + mxLo.w * wa2.w
                             + mxHi.x * wb2.x + mxHi.y * wb2.y + mxHi.z * wb2.z + mxHi.w * wb2.w;
                    }
                    fold8_2(A, B, sub);
                    Hx_a = A[0]; Hx_b = B[0];
                }
                float H_a = fmaxf(Hm_a + b1a, 0.0f) + fmaxf(Hx_a + b1a, 0.0f);
                float H_b = fmaxf(Hm_b + b1b, 0.0f) + fmaxf(Hx_b + b1b, 0.0f);

                float4 a0 = {0.f, 0.f, 0.f, 0.f}, a1 = {0.f, 0.f, 0.f, 0.f};
                #pragma unroll
                for (int h = 0; h < 8; ++h) {
                    float Hh = __shfl(H_a, h, 8);
                    float4 w0 = w2q[h * 16 + 2 * sub], w1v = w2q[h * 16 + 2 * sub + 1];
                    a0.x += Hh * w0.x; a0.y += Hh * w0.y; a0.z += Hh * w0.z; a0.w += Hh * w0.w;
                    a1.x += Hh * w1v.x; a1.y += Hh * w1v.y; a1.z += Hh * w1v.z; a1.w += Hh * w1v.w;
                }
                #pragma unroll
                for (int h = 0; h < 8; ++h) {
                    float Hh = __shfl(H_b, h, 8);
                    float4 w0 = w2q[(h + 8) * 16 + 2 * sub], w1v = w2q[(h + 8) * 16 + 2 * sub + 1];
                    a0.x += Hh * w0.x; a0.y += Hh * w0.y; a0.z += Hh * w0.z; a0.w += Hh * w0.w;
                    a1.x += Hh * w1v.x; a1.y += Hh * w1v.y; a1.z += Hh * w1v.z; a1.w += Hh * w1v.w;
                }
                float4 o0, o1;
                o0.x = own0.x * sigmoidf_(a0.x + 2.0f * bq0.x);
                o0.y = own0.y * sigmoidf_(a0.y + 2.0f * bq0.y);
                o0.z = own0.z * sigmoidf_(a0.z + 2.0f * bq0.z);
                o0.w = own0.w * sigmoidf_(a0.w + 2.0f * bq0.w);
                o1.x = own1.x * sigmoidf_(a1.x + 2.0f * bq1.x);
                o1.y = own1.y * sigmoidf_(a1.y + 2.0f * bq1.y);
                o1.z = own1.z * sigmoidf_(a1.z + 2.0f * bq1.z);
                o1.w = own1.w * sigmoidf_(a1.w + 2.0f * bq1.w);
                outse[(size_t)p * 16 + 2 * sub] = o0;
                outse[(size_t)p * 16 + 2 * sub + 1] = o1;

                float sm = (o0.x + o0.y + o0.z + o0.w) + (o1.x + o1.y + o1.z + o1.w);
                float sx = fmaxf(fmaxf(fmaxf(o0.x, o0.y), fmaxf(o0.z, o0.w)),
                                 fmaxf(fmaxf(o1.x, o1.y), fmaxf(o1.z, o1.w)));
                #pragma unroll
                for (int m = 4; m >= 1; m >>= 1) {
                    sm += __shfl_xor(sm, m);
                    sx = fmaxf(sx, __shfl_xor(sx, m));
                }
                if (sub == 0) rowstat[p] = make_float2(sm * (1.0f / 64.0f), sx);
            }
        }
    }
    grid.sync();

    // ---- phase B: knn stats pooling (2 lanes/point) ----
    {
        const int4* idxv = (const int4*)idx;
        int two_n = 2 * n;
        for (int tt = gid; tt < two_n; tt += gsz) {
            int i = tt >> 1, half = tt & 1;
            int4 a = idxv[(size_t)i * 4 + half * 2];
            int4 b = idxv[(size_t)i * 4 + half * 2 + 1];
            float2 s0 = rowstat[a.x], s1 = rowstat[a.y], s2 = rowstat[a.z], s3 = rowstat[a.w];
            float2 s4 = rowstat[b.x], s5 = rowstat[b.y], s6 = rowstat[b.z], s7 = rowstat[b.w];
            float zm = (s0.x + s1.x) + (s2.x + s3.x) + ((s4.x + s5.x) + (s6.x + s7.x));
            float zx = fmaxf(fmaxf(fmaxf(s0.y, s1.y), fmaxf(s2.y, s3.y)),
                             fmaxf(fmaxf(s4.y, s5.y), fmaxf(s6.y, s7.y)));
            zm += __shfl_xor(zm, 1);
            zx = fmaxf(zx, __shfl_xor(zx, 1));
            if (half == 0) zz[i] = make_float2(zm * (1.0f / 16.0f), zx);
        }
    }
    grid.sync();

    // ---- phase C: 27-tap sparse conv -> sigmoid gate -> scale outse ----
    {
        int nCh = (n + 255) / 256;
        for (int c = blockIdx.x; c < nCh; c += gridDim.x) {
            int base = c * 256;
            int i = base + t;
            if (i < n) {
                float acc = 0.0f;
                #pragma unroll
                for (int k = 0; k < 27; ++k) {
                    int j = cidx[(size_t)i * 27 + k];   // branchless clamp + mask
                    int jc = j >= 0 ? j : 0;
                    float msk = j >= 0 ? 1.0f : 0.0f;
                    float2 zv = zz[jc];
                    acc += msk * (zv.x * cw[2 * k] + zv.y * cw[2 * k + 1]);
                }
                sgate[t] = sigmoidf_(acc);
            }
            __syncthreads();
            int npts = n - base; if (npts > 256) npts = 256;
            int tot = npts * 16;                        // float4s this chunk owns
            for (int q = t; q < tot; q += 256) {
                float s = sgate[q >> 4];
                float4 v = outse[(size_t)base * 16 + q];
                out[(size_t)base * 16 + q] = make_float4(v.x * s, v.y * s, v.z * s, v.w * s);
            }
            __syncthreads();   // protect sgate before next chunk reuses it
        }
    }
}

extern "C" void kernel_launch(void* const* d_in, const int* in_sizes, int n_in,
                              void* d_out, int out_size, void* d_ws, size_t ws_size,
                              hipStream_t stream) {
    const float* x_F    = (const float*)d_in[0];
    const float* W1     = (const float*)d_in[1];
    const float* b1     = (const float*)d_in[2];
    const float* W2     = (const float*)d_in[3];
    const float* b2     = (const float*)d_in[4];
    const float* conv_w = (const float*)d_in[5];
    const int*   idx    = (const int*)d_in[6];
    const int*   cidx   = (const int*)d_in[7];
    int n = in_sizes[0] / CH;   // 100000

    char* ws = (char*)d_ws;
    size_t off = 0;
    uint2*  xb      = (uint2*)(ws + off);  off += (size_t)n * CH * 2;   // bf16 table
    float*  outse   = (float*)(ws + off);  off += (size_t)n * CH * 4;
    float2* rowstat = (float2*)(ws + off); off += (size_t)n * 8;
    float2* zz      = (float2*)(ws + off); off += (size_t)n * 8;

    const float4* xv = (const float4*)x_F;
    float4* outsev = (float4*)outse;
    float4* outv = (float4*)d_out;

    // co-resident grid: occupancy query (pure host-side, deterministic)
    int perCU = 0;
    hipError_t e = hipOccupancyMaxActiveBlocksPerMultiprocessor(
        &perCU, reinterpret_cast<const void*>(kFused), 256, 0);
    if (e != hipSuccess || perCU < 1) perCU = 2;
    if (perCU > 8) perCU = 8;
    int grid = perCU * 256;   // 256 CUs on MI355X

    void* args[] = {(void*)&xv, (void*)&xb, (void*)&W1, (void*)&b1, (void*)&W2,
                    (void*)&b2, (void*)&idx, (void*)&cidx, (void*)&conv_w,
                    (void*)&outsev, (void*)&rowstat, (void*)&zz, (void*)&outv,
                    (void*)&n};
    hipLaunchCooperativeKernel(reinterpret_cast<void*>(kFused),
                               dim3(grid), dim3(256), args, 0, stream);
}